// Round 5
// baseline (441.360 us; speedup 1.0000x reference)
//
#include <hip/hip_runtime.h>

#define NPIX (8 * 1024 * 1024)
#define IN 8
#define HID 16
#define OUTC 3
#define BLK 256
#define PPT 2                 // pixels per thread per iteration (one "pair")
#define GRID 1024             // persistent blocks: 4 per CU at 4 waves/SIMD
#define NITER (NPIX / (GRID * BLK * PPT))   // 16

// f16x2 pair type for v_dot2_f32_f16 (fdot2 accepts _Float16 vectors;
// cvt_pkrtz returns __fp16 vectors -> bit_cast between them, both 4 B).
typedef _Float16 f16x2 __attribute__((ext_vector_type(2)));

__device__ __forceinline__ f16x2 pkrtz(float lo, float hi) {
    return __builtin_bit_cast(f16x2, __builtin_amdgcn_cvt_pkrtz(lo, hi));
}

// d_ws layout (u32-indexed):
// [0] mask-format flag; weights transposed + packed as f16x2 pairs so each
// output-neuron row is contiguous -> uniform s_load into SGPRs, hoisted
// out of the persistent loop (loop-invariant).
#define WS_W0H 16    // 16 rows x 4 u32   (w0^T, f16 pairs over IN)
#define WS_W1H 80    // 16 rows x 8 u32   (w1^T, f16 pairs over HID)
#define WS_W2H 208   //  3 rows x 8 u32   (w2^T)
#define WS_B0  240   // f32 x16
#define WS_B1  256   // f32 x16
#define WS_B2  272   // f32 x3

__device__ __forceinline__ unsigned int pack2(float lo, float hi) {
    _Float16 a = (_Float16)lo, b = (_Float16)hi;
    unsigned short ua = __builtin_bit_cast(unsigned short, a);
    unsigned short ub = __builtin_bit_cast(unsigned short, b);
    return (unsigned int)ua | ((unsigned int)ub << 16);
}

__global__ void prep_kernel(const unsigned int* __restrict__ m,
                            const float* __restrict__ w0, const float* __restrict__ b0,
                            const float* __restrict__ w1, const float* __restrict__ b1,
                            const float* __restrict__ w2, const float* __restrict__ b2,
                            float* __restrict__ ws) {
    const int t = threadIdx.x;  // 256
    unsigned int* wsu = (unsigned int*)ws;
    if (t < 64) {  // mask format detect: packed bool bytes give u32 words > 1 a.s.
        unsigned int acc = 0u;
        #pragma unroll
        for (int k = 0; k < 8; ++k) acc |= m[t * 8 + k];
        const unsigned long long big = __ballot(acc > 1u);
        if (t == 0) ((int*)ws)[0] = big ? 1 : 0;   // 1 => byte-mask
    }
    if (t < 64)  { int j = t >> 2, k = t & 3;
        wsu[WS_W0H + j * 4 + k] = pack2(w0[(2 * k) * HID + j], w0[(2 * k + 1) * HID + j]); }
    if (t < 128) { int j = t >> 3, k = t & 7;
        wsu[WS_W1H + j * 8 + k] = pack2(w1[(2 * k) * HID + j], w1[(2 * k + 1) * HID + j]); }
    if (t < 24)  { int j = t >> 3, k = t & 7;
        wsu[WS_W2H + j * 8 + k] = pack2(w2[(2 * k) * OUTC + j], w2[(2 * k + 1) * OUTC + j]); }
    if (t < HID)  { ws[WS_B0 + t] = b0[t]; ws[WS_B1 + t] = b1[t]; }
    if (t < OUTC) { ws[WS_B2 + t] = b2[t]; }
}

// Compute one pixel-pair from registers and store 6 floats (24 B, 8B-aligned)
// directly to global. No LDS, no __syncthreads -> prefetch loads stay in
// flight across iterations (syncthreads would force a vmcnt(0) drain).
__device__ __forceinline__ void compute_store_pair(
    const unsigned int* __restrict__ wsu, const float* __restrict__ ws,
    float* __restrict__ out, unsigned int pr,
    float4 x0a, float4 x1a, float4 x0b, float4 x1b, int ma, int mb)
{
    const float4 x0[PPT] = { x0a, x0b };
    const float4 x1[PPT] = { x1a, x1b };
    const int    mv[PPT] = { ma, mb };

    // pack x to f16 pairs
    f16x2 xh[PPT][4];
    #pragma unroll
    for (int p = 0; p < PPT; ++p) {
        xh[p][0] = pkrtz(x0[p].x, x0[p].y);
        xh[p][1] = pkrtz(x0[p].z, x0[p].w);
        xh[p][2] = pkrtz(x1[p].x, x1[p].y);
        xh[p][3] = pkrtz(x1[p].z, x1[p].w);
    }

    // layer 0
    f16x2 h0h[PPT][HID / 2];
    {
        float h0[PPT][HID];
        #pragma unroll
        for (int j = 0; j < HID; ++j) {
            f16x2 w[4];
            #pragma unroll
            for (int k = 0; k < 4; ++k) w[k] = __builtin_bit_cast(f16x2, wsu[WS_W0H + j * 4 + k]);
            const float bj = ws[WS_B0 + j];
            #pragma unroll
            for (int p = 0; p < PPT; ++p) {
                float acc = bj;
                #pragma unroll
                for (int k = 0; k < 4; ++k) acc = __builtin_amdgcn_fdot2(xh[p][k], w[k], acc, false);
                h0[p][j] = fmaxf(acc, 0.0f);
            }
        }
        #pragma unroll
        for (int p = 0; p < PPT; ++p)
            #pragma unroll
            for (int i = 0; i < HID / 2; ++i)
                h0h[p][i] = pkrtz(h0[p][2 * i], h0[p][2 * i + 1]);
    }

    // layer 1
    f16x2 h1h[PPT][HID / 2];
    {
        float h1[PPT][HID];
        #pragma unroll
        for (int j = 0; j < HID; ++j) {
            f16x2 w[8];
            #pragma unroll
            for (int k = 0; k < 8; ++k) w[k] = __builtin_bit_cast(f16x2, wsu[WS_W1H + j * 8 + k]);
            const float bj = ws[WS_B1 + j];
            #pragma unroll
            for (int p = 0; p < PPT; ++p) {
                float acc = bj;
                #pragma unroll
                for (int k = 0; k < 8; ++k) acc = __builtin_amdgcn_fdot2(h0h[p][k], w[k], acc, false);
                h1[p][j] = fmaxf(acc, 0.0f);
            }
        }
        #pragma unroll
        for (int p = 0; p < PPT; ++p)
            #pragma unroll
            for (int i = 0; i < HID / 2; ++i)
                h1h[p][i] = pkrtz(h1[p][2 * i], h1[p][2 * i + 1]);
    }

    // layer 2 + sigmoid + blend
    float ov[PPT][OUTC];
    #pragma unroll
    for (int p = 0; p < PPT; ++p) {
        const float res = x0[p].w;
        #pragma unroll
        for (int j = 0; j < OUTC; ++j) {
            float acc = ws[WS_B2 + j];
            #pragma unroll
            for (int k = 0; k < 8; ++k)
                acc = __builtin_amdgcn_fdot2(h1h[p][k],
                        __builtin_bit_cast(f16x2, wsu[WS_W2H + j * 8 + k]), acc, false);
            float e = __expf(-acc);
            float y = __builtin_amdgcn_rcpf(1.0f + e);
            float rgb = (j == 0) ? x0[p].x : (j == 1) ? x0[p].y : x0[p].z;
            float bl = fmaf(res, y - rgb, rgb);      // (1-res)*rgb + res*y
            ov[p][j] = mv[p] ? bl : 0.0f;
        }
    }

    // direct store: 24 B at out + pr*6 floats, 8B-aligned -> 3x dwordx2
    float2* op = (float2*)(out + (size_t)pr * (PPT * OUTC));
    op[0] = make_float2(ov[0][0], ov[0][1]);
    op[1] = make_float2(ov[0][2], ov[1][0]);
    op[2] = make_float2(ov[1][1], ov[1][2]);
}

// Persistent grid-stride kernel: 1024 blocks, each thread handles 16
// pixel-pairs with register double-buffered prefetch (A/B named buffers so
// every index is compile-time-static; runtime-indexed buffers go to scratch).
// Weight s_loads are loop-invariant -> paid once per wave, not 16x.
__global__ void __launch_bounds__(BLK, 3) colormlp_kernel(
    const float* __restrict__ x,
    const void*  __restrict__ mask,
    const float* __restrict__ ws,
    float* __restrict__ out)
{
    const int t = threadIdx.x;
    const unsigned int* wsu = (const unsigned int*)ws;
    const int mflag = ((const int*)ws)[0];
    const unsigned int stride = GRID * BLK;              // pairs per iteration

    unsigned int prA = blockIdx.x * BLK + t;

    float4 A0a, A1a, A0b, A1b, B0a, B1a, B0b, B1b;
    int mAa, mAb, mBa, mBb;

    // x layout per pair pr: 4 consecutive float4 at xp + pr*4 (64 B/lane,
    // contiguous 4 KB per wave per iteration).
    const float4* xp = (const float4*)x;

#define LOADX(P0a, P1a, P0b, P1b, MA, MB, pr) do {                              \
        const float4* _b = xp + (size_t)(pr) * 4;                               \
        P0a = _b[0]; P1a = _b[1]; P0b = _b[2]; P1b = _b[3];                     \
        if (mflag) {                                                            \
            uchar2 _m = *(const uchar2*)((const unsigned char*)mask + (size_t)(pr) * 2); \
            MA = _m.x; MB = _m.y;                                               \
        } else {                                                                \
            int2 _m = *(const int2*)((const int*)mask + (size_t)(pr) * 2);      \
            MA = _m.x; MB = _m.y;                                               \
        }                                                                       \
    } while (0)

    LOADX(A0a, A1a, A0b, A1b, mAa, mAb, prA);

    #pragma unroll 1
    for (int i = 0; i < NITER; i += 2) {
        const unsigned int prB = prA + stride;
        // prefetch B while computing A (NITER even -> B always in range)
        LOADX(B0a, B1a, B0b, B1b, mBa, mBb, prB);
        compute_store_pair(wsu, ws, out, prA, A0a, A1a, A0b, A1b, mAa, mAb);

        const unsigned int prA2 = prB + stride;
        if (i + 2 < NITER)   // uniform scalar branch
            LOADX(A0a, A1a, A0b, A1b, mAa, mAb, prA2);
        compute_store_pair(wsu, ws, out, prB, B0a, B1a, B0b, B1b, mBa, mBb);
        prA = prA2;
    }
#undef LOADX
}

extern "C" void kernel_launch(void* const* d_in, const int* in_sizes, int n_in,
                              void* d_out, int out_size, void* d_ws, size_t ws_size,
                              hipStream_t stream) {
    const float* x    = (const float*)d_in[0];
    const void*  mask = d_in[1];
    const float* w0   = (const float*)d_in[2];
    const float* b0   = (const float*)d_in[3];
    const float* w1   = (const float*)d_in[4];
    const float* b1   = (const float*)d_in[5];
    const float* w2   = (const float*)d_in[6];
    const float* b2   = (const float*)d_in[7];
    float* out = (float*)d_out;
    float* ws  = (float*)d_ws;

    prep_kernel<<<1, BLK, 0, stream>>>((const unsigned int*)mask,
                                       w0, b0, w1, b1, w2, b2, ws);

    colormlp_kernel<<<GRID, BLK, 0, stream>>>(x, mask, ws, out);
}